// Round 15
// baseline (278.141 us; speedup 1.0000x reference)
//
#include <hip/hip_runtime.h>

// ROI pooling: bilinear resize each (h,w) crop to 7x7 over 256 channels.
// img: (200,200,256) f32 NHWC; rois: (2000,4) int32 (x,y,w,h); out: (2000,7,7,256) f32.
//
// R15: per-XCD dynamic work stealing.
// Ledger: ylo-sort -15us, XCD-chunk -3, NT-store -2; all ILP/occupancy-shape/
// finer-key changes neutral. R11 counter Occupancy=43% with no cap binding =>
// completion-variance tail (static assignment, no backfill). Fix: 8 per-XCD
// atomic counters; each wave steals 1 sorted pair at a time from its XCD's
// contiguous chunk. Early finishers backfill; per-XCD instantaneous read
// window narrows to ~3MB (< 4MB L2). Low-VGPR body (~40) so 8 waves/SIMD.
//  K1: ylo counting sort (200 bins, wave-parallel scan) + zero the counters.
//  K2: 2048 blocks x 4 waves; wave: steal pair, process, repeat. NT stores.

typedef float f32x4 __attribute__((ext_vector_type(4)));

#define NPAIRS 14000
#define PERXCD (NPAIRS / 8)   // 1750

// ---- K1: counting sort of pairs by ylo into perm (d_ws); zero ctrs ----------
__global__ __launch_bounds__(1024) void roi_sort_kernel(
    const int* __restrict__ rois, int R, int* __restrict__ perm,
    int* __restrict__ ctr)
{
    __shared__ int cnt[256];
    const int tid   = threadIdx.x;
    const int pairs = R * 7;

    if (tid < 256) cnt[tid] = 0;
    if (tid >= 1016) ctr[tid - 1016] = 0;    // zero the 8 steal counters
    __syncthreads();

    for (int p = tid; p < pairs; p += 1024) {
        const int r  = p / 7;
        const int py = p - r * 7;
        const int y  = rois[4 * r + 1];
        const int h  = rois[4 * r + 3];
        const float ty = ((float)py + 0.5f) * ((float)h / 7.0f) - 0.5f;
        const int  iy  = (int)floorf(ty);
        const int  ylo = min(max(iy, 0), h - 1) + y;   // in [0,199]
        atomicAdd(&cnt[ylo], 1);
    }
    __syncthreads();

    if (tid < 64) {   // exclusive scan over 256 bins (wave 0)
        const int b  = tid << 2;
        const int v0 = cnt[b], v1 = cnt[b + 1], v2 = cnt[b + 2], v3 = cnt[b + 3];
        const int tot = v0 + v1 + v2 + v3;
        int inc = tot;
        #pragma unroll
        for (int off = 1; off < 64; off <<= 1) {
            const int t = __shfl_up(inc, off);
            if (tid >= off) inc += t;
        }
        const int excl = inc - tot;
        cnt[b]     = excl;
        cnt[b + 1] = excl + v0;
        cnt[b + 2] = excl + v0 + v1;
        cnt[b + 3] = excl + v0 + v1 + v2;
    }
    __syncthreads();

    for (int p = tid; p < pairs; p += 1024) {
        const int r  = p / 7;
        const int py = p - r * 7;
        const int y  = rois[4 * r + 1];
        const int h  = rois[4 * r + 3];
        const float ty = ((float)py + 0.5f) * ((float)h / 7.0f) - 0.5f;
        const int  iy  = (int)floorf(ty);
        const int  ylo = min(max(iy, 0), h - 1) + y;
        const int  pos = atomicAdd(&cnt[ylo], 1);
        perm[pos] = p;
    }
}

// ---- K2: dynamic stealing, 1 pair per steal, simple low-VGPR body -----------
__global__ __launch_bounds__(256, 8) void roi_pool_kernel(
    const float* __restrict__ img,
    const int*   __restrict__ rois,
    const int*   __restrict__ perm,
    int*         __restrict__ ctr,
    float*       __restrict__ out)
{
    constexpr int P = 7;
    constexpr int C = 256;
    constexpr int W = 200;

    const int xcd  = blockIdx.x & 7;      // blocks round-robin across XCDs
    const int lane = threadIdx.x & 63;
    const int c    = lane << 2;           // 4 channels/lane

    for (;;) {
        int t;
        if (lane == 0) t = atomicAdd(&ctr[xcd], 1);
        t = __shfl(t, 0);
        if (t >= PERXCD) return;

        const int p  = perm[xcd * PERXCD + t];
        const int r  = p / 7;
        const int py = p - r * 7;

        const int x = rois[4 * r + 0];
        const int y = rois[4 * r + 1];
        const int w = rois[4 * r + 2];
        const int h = rois[4 * r + 3];

        const float ty = ((float)py + 0.5f) * ((float)h / (float)P) - 0.5f;
        const float fy = floorf(ty);
        const float wy = ty - fy;
        const int   iy = (int)fy;
        const int   ylo = min(max(iy,     0), h - 1) + y;
        const int   yhi = min(max(iy + 1, 0), h - 1) + y;

        const float* row0 = img + (long)ylo * W * C + c;
        const float* row1 = img + (long)yhi * W * C + c;
        const float  sx   = (float)w / (float)P;

        float* out_row = out + ((long)r * P + py) * P * C + c;

        #pragma unroll
        for (int px = 0; px < P; ++px) {
            const float tx = ((float)px + 0.5f) * sx - 0.5f;
            const float fx = floorf(tx);
            const float wx = tx - fx;
            const int   ix = (int)fx;
            const int   xlo = (min(max(ix,     0), w - 1) + x) * C;
            const int   xhi = (min(max(ix + 1, 0), w - 1) + x) * C;

            const f32x4 v00 = *(const f32x4*)(row0 + xlo);
            const f32x4 v01 = *(const f32x4*)(row0 + xhi);
            const f32x4 v10 = *(const f32x4*)(row1 + xlo);
            const f32x4 v11 = *(const f32x4*)(row1 + xhi);

            const f32x4 top = v00 + (v01 - v00) * wx;
            const f32x4 bot = v10 + (v11 - v10) * wx;
            const f32x4 res = top + (bot - top) * wy;

            __builtin_nontemporal_store(res, (f32x4*)(out_row + px * C));
        }
    }
}

extern "C" void kernel_launch(void* const* d_in, const int* in_sizes, int n_in,
                              void* d_out, int out_size, void* d_ws, size_t ws_size,
                              hipStream_t stream) {
    const float* img  = (const float*)d_in[0];
    const int*   rois = (const int*)d_in[1];
    float*       out  = (float*)d_out;
    int*         perm = (int*)d_ws;
    int*         ctr  = perm + NPAIRS;    // 8 ints after the 14000-entry perm

    const int R = in_sizes[1] / 4;        // 2000

    roi_sort_kernel<<<1, 1024, 0, stream>>>(rois, R, perm, ctr);
    roi_pool_kernel<<<2048, 256, 0, stream>>>(img, rois, perm, ctr, out);
}

// Round 16
// 70.331 us; speedup vs baseline: 3.9547x; 3.9547x over previous
//
#include <hip/hip_runtime.h>

// ROI pooling: bilinear resize each (h,w) crop to 7x7 over 256 channels.
// img: (200,200,256) f32 NHWC; rois: (2000,4) int32 (x,y,w,h); out: (2000,7,7,256) f32.
//
// R16: per-XCD dynamic stealing, FIXED: R15 died of same-cacheline cross-XCD
// atomic ping-pong (8 counters in one 64B line, ~10K serialized line moves,
// 278us). Now: counters padded 256B apart (each stays home in its XCD's L2)
// and steal granularity G=7 pairs/atomic (~250 atomics/counter total). Each
// wave's 7 sequential pairs also average out per-pair cache-luck variance.
//  K1: ylo counting sort (200 bins, wave-parallel scan) + zero padded ctrs.
//  K2: 2048 blocks x 4 waves; wave: steal 7 sorted pairs, process, repeat.
//      Bijective per-XCD chunks of the sorted perm; NT stores; VGPR-lean body.

typedef float f32x4 __attribute__((ext_vector_type(4)));

#define NPAIRS 14000
#define PERXCD (NPAIRS / 8)   // 1750
#define GRAIN  7              // pairs per steal
#define CTR_STRIDE 64         // ints: 256B between counters -> distinct lines

// ---- K1: counting sort of pairs by ylo into perm (d_ws); zero ctrs ----------
__global__ __launch_bounds__(1024) void roi_sort_kernel(
    const int* __restrict__ rois, int R, int* __restrict__ perm,
    int* __restrict__ ctr)
{
    __shared__ int cnt[256];
    const int tid   = threadIdx.x;
    const int pairs = R * 7;

    if (tid < 256) cnt[tid] = 0;
    if (tid < 8 * CTR_STRIDE) ctr[tid] = 0;   // zero padded steal counters
    __syncthreads();

    for (int p = tid; p < pairs; p += 1024) {
        const int r  = p / 7;
        const int py = p - r * 7;
        const int y  = rois[4 * r + 1];
        const int h  = rois[4 * r + 3];
        const float ty = ((float)py + 0.5f) * ((float)h / 7.0f) - 0.5f;
        const int  iy  = (int)floorf(ty);
        const int  ylo = min(max(iy, 0), h - 1) + y;   // in [0,199]
        atomicAdd(&cnt[ylo], 1);
    }
    __syncthreads();

    if (tid < 64) {   // exclusive scan over 256 bins (wave 0)
        const int b  = tid << 2;
        const int v0 = cnt[b], v1 = cnt[b + 1], v2 = cnt[b + 2], v3 = cnt[b + 3];
        const int tot = v0 + v1 + v2 + v3;
        int inc = tot;
        #pragma unroll
        for (int off = 1; off < 64; off <<= 1) {
            const int t = __shfl_up(inc, off);
            if (tid >= off) inc += t;
        }
        const int excl = inc - tot;
        cnt[b]     = excl;
        cnt[b + 1] = excl + v0;
        cnt[b + 2] = excl + v0 + v1;
        cnt[b + 3] = excl + v0 + v1 + v2;
    }
    __syncthreads();

    for (int p = tid; p < pairs; p += 1024) {
        const int r  = p / 7;
        const int py = p - r * 7;
        const int y  = rois[4 * r + 1];
        const int h  = rois[4 * r + 3];
        const float ty = ((float)py + 0.5f) * ((float)h / 7.0f) - 0.5f;
        const int  iy  = (int)floorf(ty);
        const int  ylo = min(max(iy, 0), h - 1) + y;
        const int  pos = atomicAdd(&cnt[ylo], 1);
        perm[pos] = p;
    }
}

// ---- K2: dynamic stealing, GRAIN sorted pairs per steal ---------------------
__global__ __launch_bounds__(256, 8) void roi_pool_kernel(
    const float* __restrict__ img,
    const int*   __restrict__ rois,
    const int*   __restrict__ perm,
    int*         __restrict__ ctr,
    float*       __restrict__ out)
{
    constexpr int P = 7;
    constexpr int C = 256;
    constexpr int W = 200;

    const int xcd  = blockIdx.x & 7;      // blocks round-robin across XCDs
    const int lane = threadIdx.x & 63;
    const int c    = lane << 2;           // 4 channels/lane

    for (;;) {
        int t;
        if (lane == 0) t = atomicAdd(&ctr[xcd * CTR_STRIDE], GRAIN);
        t = __shfl(t, 0);
        if (t >= PERXCD) return;
        const int tend = min(t + GRAIN, PERXCD);

        for (; t < tend; ++t) {
            const int p  = perm[xcd * PERXCD + t];
            const int r  = p / 7;
            const int py = p - r * 7;

            const int x = rois[4 * r + 0];
            const int y = rois[4 * r + 1];
            const int w = rois[4 * r + 2];
            const int h = rois[4 * r + 3];

            const float ty = ((float)py + 0.5f) * ((float)h / (float)P) - 0.5f;
            const float fy = floorf(ty);
            const float wy = ty - fy;
            const int   iy = (int)fy;
            const int   ylo = min(max(iy,     0), h - 1) + y;
            const int   yhi = min(max(iy + 1, 0), h - 1) + y;

            const float* row0 = img + (long)ylo * W * C + c;
            const float* row1 = img + (long)yhi * W * C + c;
            const float  sx   = (float)w / (float)P;

            float* out_row = out + ((long)r * P + py) * P * C + c;

            #pragma unroll
            for (int px = 0; px < P; ++px) {
                const float tx = ((float)px + 0.5f) * sx - 0.5f;
                const float fx = floorf(tx);
                const float wx = tx - fx;
                const int   ix = (int)fx;
                const int   xlo = (min(max(ix,     0), w - 1) + x) * C;
                const int   xhi = (min(max(ix + 1, 0), w - 1) + x) * C;

                const f32x4 v00 = *(const f32x4*)(row0 + xlo);
                const f32x4 v01 = *(const f32x4*)(row0 + xhi);
                const f32x4 v10 = *(const f32x4*)(row1 + xlo);
                const f32x4 v11 = *(const f32x4*)(row1 + xhi);

                const f32x4 top = v00 + (v01 - v00) * wx;
                const f32x4 bot = v10 + (v11 - v10) * wx;
                const f32x4 res = top + (bot - top) * wy;

                __builtin_nontemporal_store(res, (f32x4*)(out_row + px * C));
            }
        }
    }
}

extern "C" void kernel_launch(void* const* d_in, const int* in_sizes, int n_in,
                              void* d_out, int out_size, void* d_ws, size_t ws_size,
                              hipStream_t stream) {
    const float* img  = (const float*)d_in[0];
    const int*   rois = (const int*)d_in[1];
    float*       out  = (float*)d_out;
    int*         perm = (int*)d_ws;
    int*         ctr  = perm + NPAIRS;    // 8 padded counters after perm

    const int R = in_sizes[1] / 4;        // 2000

    roi_sort_kernel<<<1, 1024, 0, stream>>>(rois, R, perm, ctr);
    roi_pool_kernel<<<2048, 256, 0, stream>>>(img, rois, perm, ctr, out);
}

// Round 17
// 39.612 us; speedup vs baseline: 7.0217x; 1.7755x over previous
//
#include <hip/hip_runtime.h>

// ROI pooling: bilinear resize each (h,w) crop to 7x7 over 256 channels.
// img: (200,200,256) f32 NHWC; rois: (2000,4) int32 (x,y,w,h); out: (2000,7,7,256) f32.
//
// R17: K2 is pinned at the per-CU vector-memory (L2-gather) wall (~490MB of
// L2-served traffic/pass at ~20B/cy/CU; invariant across 6 structural
// variants, R7-R16). Last non-wall residual: K1 + launch overhead (~4-6us).
// K1 v2 computes each pair's ylo ONCE, caches it as u8 in LDS (14KB), so the
// scatter pass is pure LDS traffic (no div/float/rois reload).
//  K1: ylo counting sort, 200 bins, wave-parallel scan, u8 ylo cache.
//  K2: = R13 best (46.06us): 1750 blocks x 4 waves x 2 sorted pairs,
//      phase-split batched loads, __launch_bounds__(256,4), bijective
//      XCD-chunked swizzle, NT stores.

typedef float f32x4 __attribute__((ext_vector_type(4)));

#define NPAIRS 14000

// ---- K1: counting sort of pairs by ylo into perm (d_ws) ---------------------
__global__ __launch_bounds__(1024) void roi_sort_kernel(
    const int* __restrict__ rois, int R, int* __restrict__ perm)
{
    __shared__ int cnt[256];
    __shared__ unsigned char pylo[NPAIRS];
    const int tid   = threadIdx.x;
    const int pairs = R * 7;

    if (tid < 256) cnt[tid] = 0;
    __syncthreads();

    // phase 1: per-ROI, compute 7 ylos, cache in LDS, histogram
    for (int r = tid; r < R; r += 1024) {
        const int y = rois[4 * r + 1];
        const int h = rois[4 * r + 3];
        const float sy = (float)h / 7.0f;
        #pragma unroll
        for (int py = 0; py < 7; ++py) {
            const float ty = ((float)py + 0.5f) * sy - 0.5f;
            const int  iy  = (int)floorf(ty);
            const int  ylo = min(max(iy, 0), h - 1) + y;   // [0,199]
            pylo[r * 7 + py] = (unsigned char)ylo;
            atomicAdd(&cnt[ylo], 1);
        }
    }
    __syncthreads();

    // phase 2: exclusive scan over 256 bins (wave 0, shfl)
    if (tid < 64) {
        const int b  = tid << 2;
        const int v0 = cnt[b], v1 = cnt[b + 1], v2 = cnt[b + 2], v3 = cnt[b + 3];
        const int tot = v0 + v1 + v2 + v3;
        int inc = tot;
        #pragma unroll
        for (int off = 1; off < 64; off <<= 1) {
            const int t = __shfl_up(inc, off);
            if (tid >= off) inc += t;
        }
        const int excl = inc - tot;
        cnt[b]     = excl;
        cnt[b + 1] = excl + v0;
        cnt[b + 2] = excl + v0 + v1;
        cnt[b + 3] = excl + v0 + v1 + v2;
    }
    __syncthreads();

    // phase 3: scatter — pure LDS (ylo from cache), one global store per pair
    for (int p = tid; p < pairs; p += 1024) {
        const int ylo = pylo[p];
        const int pos = atomicAdd(&cnt[ylo], 1);
        perm[pos] = p;
    }
}

// ---- K2: phase-split deep-batched loads, 2 pairs per wave (= R13 best) ------
__global__ __launch_bounds__(256, 4) void roi_pool_kernel(
    const float* __restrict__ img,
    const int*   __restrict__ rois,
    const int*   __restrict__ perm,
    float*       __restrict__ out)
{
    constexpr int P = 7;
    constexpr int C = 256;
    constexpr int W = 200;

    // bijective XCD-chunk swizzle (m204): each XCD owns a contiguous chunk
    const int nwg  = gridDim.x;
    const int q    = nwg >> 3;
    const int rr   = nwg & 7;
    const int xcd  = blockIdx.x & 7;
    const int base = (xcd < rr) ? xcd * (q + 1) : rr * (q + 1) + (xcd - rr) * q;
    const int bid  = base + (blockIdx.x >> 3);

    const int wave = threadIdx.x >> 6;
    const int c    = (threadIdx.x & 63) << 2;      // 4 channels/lane

    #pragma unroll
    for (int k = 0; k < 2; ++k) {
        const int pidx = bid * 8 + wave * 2 + k;   // grid exactly covers 14000

        const int p  = perm[pidx];
        const int r  = p / 7;
        const int py = p - r * 7;

        const int x = rois[4 * r + 0];
        const int y = rois[4 * r + 1];
        const int w = rois[4 * r + 2];
        const int h = rois[4 * r + 3];

        const float ty = ((float)py + 0.5f) * ((float)h / (float)P) - 0.5f;
        const float fy = floorf(ty);
        const float wy = ty - fy;
        const int   iy = (int)fy;
        const int   ylo = min(max(iy,     0), h - 1) + y;
        const int   yhi = min(max(iy + 1, 0), h - 1) + y;

        const float* row0 = img + (long)ylo * W * C + c;
        const float* row1 = img + (long)yhi * W * C + c;
        const float  sx   = (float)w / (float)P;

        float wxs[P];
        int   xls[P], xhs[P];
        #pragma unroll
        for (int px = 0; px < P; ++px) {
            const float tx = ((float)px + 0.5f) * sx - 0.5f;
            const float fx = floorf(tx);
            wxs[px] = tx - fx;
            const int ix = (int)fx;
            xls[px] = (min(max(ix,     0), w - 1) + x) * C;
            xhs[px] = (min(max(ix + 1, 0), w - 1) + x) * C;
        }

        // ---- phase A: all 14 row0 loads in flight, then horizontal interp --
        f32x4 a0[P], a1[P];
        #pragma unroll
        for (int px = 0; px < P; ++px) {
            a0[px] = *(const f32x4*)(row0 + xls[px]);
            a1[px] = *(const f32x4*)(row0 + xhs[px]);
        }
        f32x4 top[P];
        #pragma unroll
        for (int px = 0; px < P; ++px)
            top[px] = a0[px] + (a1[px] - a0[px]) * wxs[px];

        // ---- phase B: all 14 row1 loads in flight, interp + store ----------
        f32x4 b0[P], b1[P];
        #pragma unroll
        for (int px = 0; px < P; ++px) {
            b0[px] = *(const f32x4*)(row1 + xls[px]);
            b1[px] = *(const f32x4*)(row1 + xhs[px]);
        }

        float* out_row = out + ((long)r * P + py) * P * C + c;
        #pragma unroll
        for (int px = 0; px < P; ++px) {
            const f32x4 bot = b0[px] + (b1[px] - b0[px]) * wxs[px];
            const f32x4 res = top[px] + (bot - top[px]) * wy;
            __builtin_nontemporal_store(res, (f32x4*)(out_row + px * C));
        }
    }
}

extern "C" void kernel_launch(void* const* d_in, const int* in_sizes, int n_in,
                              void* d_out, int out_size, void* d_ws, size_t ws_size,
                              hipStream_t stream) {
    const float* img  = (const float*)d_in[0];
    const int*   rois = (const int*)d_in[1];
    float*       out  = (float*)d_out;
    int*         perm = (int*)d_ws;

    const int R      = in_sizes[1] / 4;   // 2000
    const int npairs = R * 7;             // 14000
    const int blocks = npairs / 8;        // 1750: 4 waves x 2 pairs, exact

    roi_sort_kernel<<<1, 1024, 0, stream>>>(rois, R, perm);
    roi_pool_kernel<<<blocks, 256, 0, stream>>>(img, rois, perm, out);
}